// Round 1
// baseline (30.084 us; speedup 1.0000x reference)
//
#include <hip/hip_runtime.h>

// Aggregation: out[b,c,oh,ow] = sum_{i,j in 0..2} xpad[b,c,oh+i,ow+j] * w[b, c%16, i*3+j, oh*64+ow]
// B=8, C=256, H=W=OH=OW=64, WC=16, G=16, K=3, PAD=1, STRIDE=1, DIL=1.

#define NB 8
#define NC 256
#define NH 64
#define NW 64
#define NWC 16
#define NG 16

__global__ __launch_bounds__(256) void agg_kernel(const float* __restrict__ x,
                                                  const float* __restrict__ wt,
                                                  float* __restrict__ out) {
    const int tid    = threadIdx.x;
    const int lane16 = tid & 15;      // 16 lanes across width
    const int row    = tid >> 4;      // 16 rows per strip
    const int bid    = blockIdx.x;
    const int strip  = bid & 3;       // 4 strips of 16 rows
    const int wc     = (bid >> 2) & 15;
    const int b      = bid >> 6;

    const int oh  = strip * 16 + row;
    const int ow0 = lane16 * 4;

    // Load this pixel-quad's 9 weight vectors once; reused for all 16 groups.
    float w[9][4];
    {
        const float* wp = wt + ((b * NWC + wc) * 9) * (NH * NW) + oh * NW + ow0;
#pragma unroll
        for (int idx = 0; idx < 9; ++idx) {
            float4 t = *reinterpret_cast<const float4*>(wp + idx * (NH * NW));
            w[idx][0] = t.x; w[idx][1] = t.y; w[idx][2] = t.z; w[idx][3] = t.w;
        }
    }

    const bool has_left  = (ow0 > 0);
    const bool has_right = (ow0 + 4 < NW);

    for (int g = 0; g < NG; ++g) {
        const int c = g * NWC + wc;
        const float* xp = x + (b * NC + c) * (NH * NW);

        float acc[4] = {0.f, 0.f, 0.f, 0.f};

#pragma unroll
        for (int i = 0; i < 3; ++i) {
            const int r = oh + i - 1;
            if (r >= 0 && r < NH) {
                const float* xr = xp + r * NW;
                float4 cv = *reinterpret_cast<const float4*>(xr + ow0);
                float e[6];
                e[0] = has_left  ? xr[ow0 - 1] : 0.f;
                e[1] = cv.x; e[2] = cv.y; e[3] = cv.z; e[4] = cv.w;
                e[5] = has_right ? xr[ow0 + 4] : 0.f;
#pragma unroll
                for (int j = 0; j < 3; ++j) {
#pragma unroll
                    for (int t = 0; t < 4; ++t) {
                        acc[t] += e[t + j] * w[i * 3 + j][t];
                    }
                }
            }
        }

        float4 o = make_float4(acc[0], acc[1], acc[2], acc[3]);
        *reinterpret_cast<float4*>(out + ((b * NC + c) * NH + oh) * NW + ow0) = o;
    }
}

extern "C" void kernel_launch(void* const* d_in, const int* in_sizes, int n_in,
                              void* d_out, int out_size, void* d_ws, size_t ws_size,
                              hipStream_t stream) {
    const float* x  = (const float*)d_in[0];
    const float* wt = (const float*)d_in[1];
    float* out      = (float*)d_out;

    // Grid: 8 batches * 16 wc * 4 strips = 512 blocks of 256 threads.
    dim3 grid(NB * NWC * 4);
    dim3 block(256);
    agg_kernel<<<grid, block, 0, stream>>>(x, wt, out);
}

// Round 2
// 29.672 us; speedup vs baseline: 1.0139x; 1.0139x over previous
//
#include <hip/hip_runtime.h>

// Aggregation: out[b,c,oh,ow] = sum_{i,j in 0..2} xpad[b,c,oh+i,ow+j] * w[b, c%16, i*3+j, oh*64+ow]
// B=8, C=256, H=W=OH=OW=64, WC=16, G=16, K=3, PAD=1, STRIDE=1, DIL=1.

#define NB 8
#define NC 256
#define NH 64
#define NW 64
#define NWC 16
#define NG 16
#define GSPLIT 4                 // groups of g per block
#define GPB (NG / GSPLIT)        // 4 g-values per thread

__global__ __launch_bounds__(256) void agg_kernel(const float* __restrict__ x,
                                                  const float* __restrict__ wt,
                                                  float* __restrict__ out) {
    const int tid    = threadIdx.x;
    const int lane16 = tid & 15;      // 16 lanes across width
    const int row    = tid >> 4;      // 16 rows per strip
    const int bid    = blockIdx.x;
    const int strip  = bid & 3;       // 4 strips of 16 rows
    const int wc     = (bid >> 2) & 15;
    const int gblk   = (bid >> 6) & (GSPLIT - 1);
    const int b      = bid >> 8;

    const int oh  = strip * 16 + row;
    const int ow0 = lane16 * 4;

    // Load this pixel-quad's 9 weight vectors once; reused for GPB groups.
    float w[9][4];
    {
        const float* wp = wt + ((b * NWC + wc) * 9) * (NH * NW) + oh * NW + ow0;
#pragma unroll
        for (int idx = 0; idx < 9; ++idx) {
            float4 t = *reinterpret_cast<const float4*>(wp + idx * (NH * NW));
            w[idx][0] = t.x; w[idx][1] = t.y; w[idx][2] = t.z; w[idx][3] = t.w;
        }
    }

    const bool has_left  = (ow0 > 0);
    const bool has_right = (ow0 + 4 < NW);

#pragma unroll
    for (int gi = 0; gi < GPB; ++gi) {
        const int g = gblk * GPB + gi;
        const int c = g * NWC + wc;
        const float* xp = x + (b * NC + c) * (NH * NW);

        float acc[4] = {0.f, 0.f, 0.f, 0.f};

#pragma unroll
        for (int i = 0; i < 3; ++i) {
            const int r = oh + i - 1;
            if (r >= 0 && r < NH) {
                const float* xr = xp + r * NW;
                float4 cv = *reinterpret_cast<const float4*>(xr + ow0);
                float e[6];
                e[0] = has_left  ? xr[ow0 - 1] : 0.f;
                e[1] = cv.x; e[2] = cv.y; e[3] = cv.z; e[4] = cv.w;
                e[5] = has_right ? xr[ow0 + 4] : 0.f;
#pragma unroll
                for (int j = 0; j < 3; ++j) {
#pragma unroll
                    for (int t = 0; t < 4; ++t) {
                        acc[t] += e[t + j] * w[i * 3 + j][t];
                    }
                }
            }
        }

        float4 o = make_float4(acc[0], acc[1], acc[2], acc[3]);
        *reinterpret_cast<float4*>(out + ((b * NC + c) * NH + oh) * NW + ow0) = o;
    }
}

extern "C" void kernel_launch(void* const* d_in, const int* in_sizes, int n_in,
                              void* d_out, int out_size, void* d_ws, size_t ws_size,
                              hipStream_t stream) {
    const float* x  = (const float*)d_in[0];
    const float* wt = (const float*)d_in[1];
    float* out      = (float*)d_out;

    // Grid: 8 batches * 16 wc * 4 gsplit * 4 strips = 2048 blocks of 256 threads.
    dim3 grid(NB * NWC * GSPLIT * 4);
    dim3 block(256);
    agg_kernel<<<grid, block, 0, stream>>>(x, wt, out);
}

// Round 3
// 23.737 us; speedup vs baseline: 1.2674x; 1.2500x over previous
//
#include <hip/hip_runtime.h>

// Aggregation: out[b,c,oh,ow] = sum_{i,j in 0..2} xpad[b,c,oh+i,ow+j] * w[b, c%16, i*3+j, oh*64+ow]
// B=8, C=256, H=W=OH=OW=64, WC=16, G=16, K=3, PAD=1, STRIDE=1, DIL=1.
//
// R3 design: LDS-staged x (each x element read from global exactly once per block,
// zero scalar global loads). Block = (b, wc, gblk of 8 channels, strip of 16 rows).
// LDS: 8 channels x 18 rows x 68 floats (64 data + 4 zero pad) = 39.2 KB -> 4 blocks/CU.

#define NB 8
#define NC 256
#define NH 64
#define NW 64
#define NWC 16
#define NG 16
#define CPB 8               // channels (g values) per block
#define GSPLIT (NG / CPB)   // 2
#define LROW 68             // padded LDS row stride in floats (64 data + 4 zero)
#define LCH (18 * LROW)     // floats per channel strip (18 rows)

__global__ __launch_bounds__(256, 4) void agg_kernel(const float* __restrict__ x,
                                                     const float* __restrict__ wt,
                                                     float* __restrict__ out) {
    __shared__ float lds[CPB * LCH];   // 9792 floats = 39168 B

    const int tid    = threadIdx.x;
    const int lane16 = tid & 15;
    const int row    = tid >> 4;       // 0..15
    const int bid    = blockIdx.x;
    const int strip  = bid & 3;
    const int wc     = (bid >> 2) & 15;
    const int gblk   = (bid >> 6) & (GSPLIT - 1);
    const int b      = bid >> 7;

    const int oh  = strip * 16 + row;
    const int ow0 = lane16 * 4;

    // ---- zero the 4 pad floats (cols 64..67) of each of the 8*18 rows ----
    if (tid < CPB * 18) {
        *reinterpret_cast<float4*>(&lds[tid * LROW + NW]) = make_float4(0.f, 0.f, 0.f, 0.f);
    }

    // ---- stage x: 8 channels x 18 rows x 16 float4 = 2304 float4, 9 per thread ----
    const int r0 = strip * 16 - 1;     // global row of LDS row 0
#pragma unroll
    for (int k = 0; k < 9; ++k) {
        const int f   = tid + k * 256;     // 0..2303
        const int ch  = f / 288;           // 288 float4 per channel
        const int rem = f - ch * 288;
        const int r   = rem >> 4;          // 0..17
        const int c4  = rem & 15;
        const int gr  = r0 + r;
        float4 v = make_float4(0.f, 0.f, 0.f, 0.f);
        if ((unsigned)gr < (unsigned)NH) {
            const int c = (gblk * CPB + ch) * NWC + wc;
            v = *reinterpret_cast<const float4*>(
                x + (((b * NC + c) * NH + gr) * NW) + c4 * 4);
        }
        *reinterpret_cast<float4*>(&lds[ch * LCH + r * LROW + c4 * 4]) = v;
    }

    // ---- load this pixel-quad's 9 weight vectors (reused for all 8 channels) ----
    float w[9][4];
    {
        const float* wp = wt + ((b * NWC + wc) * 9) * (NH * NW) + oh * NW + ow0;
#pragma unroll
        for (int idx = 0; idx < 9; ++idx) {
            float4 t = *reinterpret_cast<const float4*>(wp + idx * (NH * NW));
            w[idx][0] = t.x; w[idx][1] = t.y; w[idx][2] = t.z; w[idx][3] = t.w;
        }
    }

    __syncthreads();

    const bool has_left = (ow0 > 0);

#pragma unroll
    for (int ch = 0; ch < CPB; ++ch) {
        const int c = (gblk * CPB + ch) * NWC + wc;
        float acc[4] = {0.f, 0.f, 0.f, 0.f};

#pragma unroll
        for (int i = 0; i < 3; ++i) {
            // thread's output row oh needs global rows oh-1+i  ->  LDS row row+i
            const float* p = &lds[ch * LCH + (row + i) * LROW];
            float4 m = *reinterpret_cast<const float4*>(p + ow0);
            float l  = has_left ? p[ow0 - 1] : 0.f;
            float rt = p[ow0 + 4];          // cols 64..67 are zeroed pad
            float e[6];
            e[0] = l; e[1] = m.x; e[2] = m.y; e[3] = m.z; e[4] = m.w; e[5] = rt;
#pragma unroll
            for (int j = 0; j < 3; ++j) {
#pragma unroll
                for (int t = 0; t < 4; ++t) {
                    acc[t] += e[t + j] * w[i * 3 + j][t];
                }
            }
        }

        float4 o = make_float4(acc[0], acc[1], acc[2], acc[3]);
        *reinterpret_cast<float4*>(out + ((b * NC + c) * NH + oh) * NW + ow0) = o;
    }
}

extern "C" void kernel_launch(void* const* d_in, const int* in_sizes, int n_in,
                              void* d_out, int out_size, void* d_ws, size_t ws_size,
                              hipStream_t stream) {
    const float* x  = (const float*)d_in[0];
    const float* wt = (const float*)d_in[1];
    float* out      = (float*)d_out;

    // Grid: 8 b * 16 wc * 2 gblk * 4 strips = 1024 blocks of 256 threads.
    dim3 grid(NB * NWC * GSPLIT * 4);
    dim3 block(256);
    agg_kernel<<<grid, block, 0, stream>>>(x, wt, out);
}